// Round 2
// 512.935 us; speedup vs baseline: 1.0720x; 1.0720x over previous
//
#include <hip/hip_runtime.h>
#include <float.h>

// ---------------------------------------------------------------------------
// L1-distance top-K (K<=3) over N=200000 rows of D=512 fp32, then mean of
// pseudo[] at the top-K indices. Memory-bound: one streaming pass over
// ukb_mat (409.6 MB, floor ~65us @ 6.3 TB/s).
//
// v2 restructure: 16 lanes per row, 4 rows per wave per iteration.
//  - per lane: 8 interleaved float4 loads (lanes 0..15 cover a contiguous
//    256B segment per instruction -> coalesced; 32 loads in flight/lane-iter
//    vs 2/row before).
//  - cross-lane reduce: 4 shfl_xor steps for 4 rows (was 6 per row = 24),
//    removing the long serial ds_swizzle dependency chain that kept the
//    memory pipe idle.
//  - nontemporal loads on the matrix stream (read-once, >> L2). NOTE:
//    __builtin_nontemporal_load needs a NATIVE vector type (ext_vector_type),
//    not HIP's float4 struct — hence fx4 below.
//  - per-wave triples merged across groups (masks 16,32 only: groups own
//    disjoint rows; lanes within a group hold identical triples), then a
//    block-level LDS merge -> 3 partials per block (24 KB workspace).
// ---------------------------------------------------------------------------

#define P1_BLOCKS       1024
#define P1_THREADS      256
#define WAVES_PER_BLOCK (P1_THREADS / 64)              // 4
#define TOTAL_WAVES     (P1_BLOCKS * WAVES_PER_BLOCK)  // 4096
#define ROWS_PER_ITER   (TOTAL_WAVES * 4)              // 16384 rows / grid step
#define NUM_PART        (P1_BLOCKS * 3)                // 3072 partials
#define DCOLS           512

typedef float fx4 __attribute__((ext_vector_type(4)));  // native vec for builtins

// Insert candidate (s, r) into sorted top-3 (d0<=d1<=d2). Ties prefer the
// smaller index (matches jax.lax.top_k stability on -dist).
__device__ __forceinline__ void top3_insert(float s, int r,
                                            float& d0, float& d1, float& d2,
                                            int& i0, int& i1, int& i2) {
    if (s < d2 || (s == d2 && r < i2)) {
        d2 = s; i2 = r;
        if (d2 < d1 || (d2 == d1 && i2 < i1)) {
            float td = d1; d1 = d2; d2 = td;
            int   ti = i1; i1 = i2; i2 = ti;
        }
        if (d1 < d0 || (d1 == d0 && i1 < i0)) {
            float td = d0; d0 = d1; d1 = td;
            int   ti = i0; i0 = i1; i1 = ti;
        }
    }
}

__global__ __launch_bounds__(P1_THREADS) void l1_top3_phase1(
        const float* __restrict__ q, const float* __restrict__ mat,
        float* __restrict__ part_d, int* __restrict__ part_i, int N) {
    const int lane = threadIdx.x & 63;
    const int sub  = lane & 15;          // position within 16-lane row group
    const int grp  = lane >> 4;          // which of 4 rows this lane works on
    const int wv   = threadIdx.x >> 6;
    const int wave = blockIdx.x * WAVES_PER_BLOCK + wv;

    // Query fragment: lane holds q columns {sub+16k : k=0..7} as float4s.
    fx4 qf[8];
    #pragma unroll
    for (int k = 0; k < 8; ++k) qf[k] = ((const fx4*)q)[sub + 16 * k];

    float d0 = FLT_MAX, d1 = FLT_MAX, d2 = FLT_MAX;
    int   i0 = -1, i1 = -1, i2 = -1;

    for (int base = wave * 4; base < N; base += ROWS_PER_ITER) {
        const int row = base + grp;
        float s;
        if (row < N) {
            const fx4* rp = (const fx4*)(mat + (size_t)row * DCOLS);
            s = 0.0f;
            #pragma unroll
            for (int k = 0; k < 8; ++k) {
                // lanes 0..15 of this group read 256B contiguous per k
                fx4 a = __builtin_nontemporal_load(rp + sub + 16 * k);
                s += fabsf(a.x - qf[k].x) + fabsf(a.y - qf[k].y)
                   + fabsf(a.z - qf[k].z) + fabsf(a.w - qf[k].w);
            }
        } else {
            s = FLT_MAX;  // sums to +inf in the group, never inserted
        }
        // 16-lane butterfly (masks < 16 stay inside the group). All lanes
        // of a group end with the same row sum.
        s += __shfl_xor(s, 1, 64);
        s += __shfl_xor(s, 2, 64);
        s += __shfl_xor(s, 4, 64);
        s += __shfl_xor(s, 8, 64);
        // rows strictly increase per lane, so strict < keeps the earliest
        // index on exact ties — matches reference tie order.
        if (row < N) top3_insert(s, row, d0, d1, d2, i0, i1, i2);
    }

    // Merge the 4 groups' triples. Only cross-group steps (16, 32) are
    // needed: lanes within a group hold IDENTICAL triples (merging those
    // would duplicate entries), groups hold disjoint row sets.
    #pragma unroll
    for (int m = 16; m <= 32; m <<= 1) {
        float pd0 = __shfl_xor(d0, m, 64);
        float pd1 = __shfl_xor(d1, m, 64);
        float pd2 = __shfl_xor(d2, m, 64);
        int   pi0 = __shfl_xor(i0, m, 64);
        int   pi1 = __shfl_xor(i1, m, 64);
        int   pi2 = __shfl_xor(i2, m, 64);
        top3_insert(pd0, pi0, d0, d1, d2, i0, i1, i2);
        top3_insert(pd1, pi1, d0, d1, d2, i0, i1, i2);
        top3_insert(pd2, pi2, d0, d1, d2, i0, i1, i2);
    }

    // Block-level merge: 4 wave triples -> 3 partials per block.
    __shared__ float swd[WAVES_PER_BLOCK * 3];
    __shared__ int   swi[WAVES_PER_BLOCK * 3];
    if (lane == 0) {
        swd[wv * 3 + 0] = d0; swi[wv * 3 + 0] = i0;
        swd[wv * 3 + 1] = d1; swi[wv * 3 + 1] = i1;
        swd[wv * 3 + 2] = d2; swi[wv * 3 + 2] = i2;
    }
    __syncthreads();
    if (threadIdx.x == 0) {
        float e0 = FLT_MAX, e1 = FLT_MAX, e2 = FLT_MAX;
        int   j0 = -1, j1 = -1, j2 = -1;
        #pragma unroll
        for (int t = 0; t < WAVES_PER_BLOCK * 3; ++t)
            top3_insert(swd[t], swi[t], e0, e1, e2, j0, j1, j2);
        part_d[blockIdx.x * 3 + 0] = e0; part_i[blockIdx.x * 3 + 0] = j0;
        part_d[blockIdx.x * 3 + 1] = e1; part_i[blockIdx.x * 3 + 1] = j1;
        part_d[blockIdx.x * 3 + 2] = e2; part_i[blockIdx.x * 3 + 2] = j2;
    }
}

__global__ __launch_bounds__(256) void top3_phase2(
        const float* __restrict__ part_d, const int* __restrict__ part_i,
        const float* __restrict__ pseudo, const int* __restrict__ Kp,
        float* __restrict__ out, int num) {
    float d0 = FLT_MAX, d1 = FLT_MAX, d2 = FLT_MAX;
    int   i0 = -1, i1 = -1, i2 = -1;

    for (int j = threadIdx.x; j < num; j += 256)
        top3_insert(part_d[j], part_i[j], d0, d1, d2, i0, i1, i2);

    __shared__ float sd[256 * 3];
    __shared__ int   si[256 * 3];
    sd[threadIdx.x * 3 + 0] = d0; si[threadIdx.x * 3 + 0] = i0;
    sd[threadIdx.x * 3 + 1] = d1; si[threadIdx.x * 3 + 1] = i1;
    sd[threadIdx.x * 3 + 2] = d2; si[threadIdx.x * 3 + 2] = i2;
    __syncthreads();

    if (threadIdx.x < 64) {  // wave 0 only — shuffles see 64 active lanes
        #pragma unroll
        for (int b = 1; b < 4; ++b) {
            int base = (threadIdx.x + b * 64) * 3;
            top3_insert(sd[base + 0], si[base + 0], d0, d1, d2, i0, i1, i2);
            top3_insert(sd[base + 1], si[base + 1], d0, d1, d2, i0, i1, i2);
            top3_insert(sd[base + 2], si[base + 2], d0, d1, d2, i0, i1, i2);
        }
        #pragma unroll
        for (int m = 32; m >= 1; m >>= 1) {
            // read partner's pre-merge triple before mutating our own
            float pd0 = __shfl_xor(d0, m, 64);
            float pd1 = __shfl_xor(d1, m, 64);
            float pd2 = __shfl_xor(d2, m, 64);
            int   pi0 = __shfl_xor(i0, m, 64);
            int   pi1 = __shfl_xor(i1, m, 64);
            int   pi2 = __shfl_xor(i2, m, 64);
            top3_insert(pd0, pi0, d0, d1, d2, i0, i1, i2);
            top3_insert(pd1, pi1, d0, d1, d2, i0, i1, i2);
            top3_insert(pd2, pi2, d0, d1, d2, i0, i1, i2);
        }
        if (threadIdx.x == 0) {
            int K = Kp[0];
            if (K < 1) K = 1;
            if (K > 3) K = 3;
            float sum = pseudo[i0];
            if (K > 1) sum += pseudo[i1];
            if (K > 2) sum += pseudo[i2];
            out[0] = sum / (float)K;
        }
    }
}

extern "C" void kernel_launch(void* const* d_in, const int* in_sizes, int n_in,
                              void* d_out, int out_size, void* d_ws, size_t ws_size,
                              hipStream_t stream) {
    const float* data_in = (const float*)d_in[0];   // [1, 512] fp32
    const float* ukb_mat = (const float*)d_in[1];   // [N, 512] fp32
    const float* pseudo  = (const float*)d_in[2];   // [N] fp32
    const int*   Kp      = (const int*)d_in[3];     // scalar int (=3)
    float*       out     = (float*)d_out;           // [1] fp32

    const int N = in_sizes[1] / DCOLS;              // 200000

    // Workspace: NUM_PART floats + NUM_PART ints (24 KB), fully overwritten
    // by phase 1 every launch before phase 2 reads it.
    float* part_d = (float*)d_ws;
    int*   part_i = (int*)((char*)d_ws + (size_t)NUM_PART * sizeof(float));

    l1_top3_phase1<<<P1_BLOCKS, P1_THREADS, 0, stream>>>(
        data_in, ukb_mat, part_d, part_i, N);
    top3_phase2<<<1, 256, 0, stream>>>(
        part_d, part_i, pseudo, Kp, out, NUM_PART);
}